// Round 3
// baseline (508.875 us; speedup 1.0000x reference)
//
#include <hip/hip_runtime.h>
#include <hip/hip_bf16.h>

#define N_NODES 50000
#define N_EDGES 800000
#define TOT_EDGES (N_EDGES + N_NODES)
#define IN_DIM 256
#define OUT_DIM 256   // HEADS * HID
#define HEADS 4
#define HID 64
#define NEG_SLOPE 0.2f

typedef __bf16 bf16x8 __attribute__((ext_vector_type(8)));
typedef float f32x4 __attribute__((ext_vector_type(4)));

__device__ __forceinline__ unsigned short f2b(float f) {
    union { float f; unsigned int i; } v; v.f = f;
    unsigned int r = v.i + 0x7fffu + ((v.i >> 16) & 1u);
    return (unsigned short)(r >> 16);
}
__device__ __forceinline__ float b2f(unsigned short u) {
    union { float f; unsigned int i; } v; v.i = ((unsigned int)u) << 16; return v.f;
}

// ---------------- K-1: runtime dtype detection ------------------------------
// flags[0]: edge_index is int64 (1) or int32 (0)
// flags[1]: float tensors are fp32 (1) or bf16 (0)
// fp32 words' low 16 bits are mantissa noise -> bits[7:14] uniform (P(sane)~14%);
// bf16-packed words' low half is a real bf16 of N(0,1) -> exponent sane ~100%.
__global__ void k_detect(const unsigned int* __restrict__ xw,
                         const int* __restrict__ ei, int* __restrict__ flags) {
    __shared__ int cnt_sane, cnt_nz;
    if (threadIdx.x == 0) { cnt_sane = 0; cnt_nz = 0; }
    __syncthreads();
    int sane = 0, nz = 0;
    for (int i = threadIdx.x; i < 4096; i += blockDim.x) {
        unsigned e = (xw[i] >> 7) & 0xFFu;
        if (e >= 100u && e <= 135u) sane++;
        if (ei[2 * i + 1] != 0) nz++;   // int64 hi-words are all 0 for ids<2^31
    }
    atomicAdd(&cnt_sane, sane);
    atomicAdd(&cnt_nz, nz);
    __syncthreads();
    if (threadIdx.x == 0) {
        flags[0] = (cnt_nz == 0) ? 1 : 0;
        flags[1] = (cnt_sane < 2048) ? 1 : 0;
    }
}

// ---------------- K0a: extract src/dst as int32 from either layout ----------
__global__ void k_extract(const void* __restrict__ ei, const int* __restrict__ flags,
                          int* __restrict__ src, int* __restrict__ dst) {
    int i = blockIdx.x * blockDim.x + threadIdx.x;
    if (i >= 2 * N_EDGES) return;
    int v;
    if (flags[0]) v = (int)((const long long*)ei)[i];
    else          v = ((const int*)ei)[i];
    if (i < N_EDGES) src[i] = v;
    else             dst[i - N_EDGES] = v;
}

// ---------------- K0b: normalize float matrix to bf16 (x and W) -------------
// one thread per 4 elements
__global__ void k_cvt_mat(const void* __restrict__ in, const int* __restrict__ flags,
                          __bf16* __restrict__ out, int n_elem) {
    int i = blockIdx.x * blockDim.x + threadIdx.x;
    if (4 * i >= n_elem) return;
    if (flags[1]) {
        float4 v = ((const float4*)in)[i];
        ushort4 o;
        o.x = f2b(v.x); o.y = f2b(v.y); o.z = f2b(v.z); o.w = f2b(v.w);
        ((ushort4*)out)[i] = o;
    } else {
        ((uint2*)out)[i] = ((const uint2*)in)[i];   // already bf16, copy 8B
    }
}

// ---------------- K0c: normalize att_src/att_dst/bias to fp32 ---------------
__global__ void k_cvt_small(const void* __restrict__ a, const void* __restrict__ b,
                            const void* __restrict__ c, const int* __restrict__ flags,
                            float* __restrict__ af, float* __restrict__ bf,
                            float* __restrict__ cf) {
    int i = threadIdx.x;   // 256 threads
    if (flags[1]) {
        af[i] = ((const float*)a)[i];
        bf[i] = ((const float*)b)[i];
        cf[i] = ((const float*)c)[i];
    } else {
        af[i] = b2f(((const unsigned short*)a)[i]);
        bf[i] = b2f(((const unsigned short*)b)[i]);
        cf[i] = b2f(((const unsigned short*)c)[i]);
    }
}

// ---------------- K1: h = x @ W (bf16 MFMA, fp32 accum, bf16 out) -----------
__global__ __launch_bounds__(256) void k_gemm(const __bf16* __restrict__ x,
                                              const __bf16* __restrict__ W,
                                              __bf16* __restrict__ h) {
    const int wave = threadIdx.x >> 6;
    const int lane = threadIdx.x & 63;
    const int c    = lane & 15;   // A-m / C-col index
    const int quad = lane >> 4;
    const int m0   = blockIdx.x * 16;
    const int n0   = wave * 64;

    f32x4 acc0 = {0.f, 0.f, 0.f, 0.f};
    f32x4 acc1 = acc0, acc2 = acc0, acc3 = acc0;
    const __bf16* arow = x + (size_t)(m0 + c) * IN_DIM;

    for (int k0 = 0; k0 < IN_DIM; k0 += 32) {
        bf16x8 a = *reinterpret_cast<const bf16x8*>(arow + k0 + quad * 8);
        bf16x8 b0, b1, b2, b3;
#pragma unroll
        for (int j = 0; j < 8; ++j) {
            const __bf16* wrow = W + (size_t)(k0 + quad * 8 + j) * OUT_DIM + n0 + c;
            b0[j] = wrow[0];
            b1[j] = wrow[16];
            b2[j] = wrow[32];
            b3[j] = wrow[48];
        }
        acc0 = __builtin_amdgcn_mfma_f32_16x16x32_bf16(a, b0, acc0, 0, 0, 0);
        acc1 = __builtin_amdgcn_mfma_f32_16x16x32_bf16(a, b1, acc1, 0, 0, 0);
        acc2 = __builtin_amdgcn_mfma_f32_16x16x32_bf16(a, b2, acc2, 0, 0, 0);
        acc3 = __builtin_amdgcn_mfma_f32_16x16x32_bf16(a, b3, acc3, 0, 0, 0);
    }
#pragma unroll
    for (int r = 0; r < 4; ++r) {
        int row = m0 + quad * 4 + r;
        __bf16* orow = h + (size_t)row * OUT_DIM + n0 + c;
        orow[0]  = (__bf16)acc0[r];
        orow[16] = (__bf16)acc1[r];
        orow[32] = (__bf16)acc2[r];
        orow[48] = (__bf16)acc3[r];
    }
}

// ---------------- K2: per-node attention logits -----------------------------
__global__ __launch_bounds__(256) void k_att(const __bf16* __restrict__ h,
                                             const float* __restrict__ att_src,
                                             const float* __restrict__ att_dst,
                                             float* __restrict__ a_src,
                                             float* __restrict__ a_dst) {
    int wave = threadIdx.x >> 6, lane = threadIdx.x & 63;
    int node = blockIdx.x * 4 + wave;
    if (node >= N_NODES) return;
    const __bf16* hr = h + (size_t)node * OUT_DIM + lane * 4;
    float ps = 0.f, pd = 0.f;
#pragma unroll
    for (int i = 0; i < 4; ++i) {
        float hv = (float)hr[i];
        ps += hv * att_src[lane * 4 + i];
        pd += hv * att_dst[lane * 4 + i];
    }
#pragma unroll
    for (int o = 8; o >= 1; o >>= 1) {
        ps += __shfl_xor(ps, o, 64);
        pd += __shfl_xor(pd, o, 64);
    }
    if ((lane & 15) == 0) {
        a_src[node * 4 + (lane >> 4)] = ps;
        a_dst[node * 4 + (lane >> 4)] = pd;
    }
}

// ---------------- CSR-by-dst construction -----------------------------------
__global__ void k_init(int* counts) {
    int i = blockIdx.x * blockDim.x + threadIdx.x;
    if (i < N_NODES) counts[i] = 1;   // self loop pre-counted
}

__global__ void k_hist(const int* __restrict__ dst, int* counts) {
    int i = blockIdx.x * blockDim.x + threadIdx.x;
    if (i < N_EDGES) atomicAdd(&counts[dst[i]], 1);
}

#define SCAN_T 1024
#define CHUNK ((N_NODES + SCAN_T - 1) / SCAN_T)
__global__ __launch_bounds__(1024) void k_scan(const int* __restrict__ counts,
                                               int* __restrict__ offsets,
                                               int* __restrict__ cursor) {
    __shared__ int sums[SCAN_T];
    int t = threadIdx.x;
    int begin = t * CHUNK;
    int end = begin + CHUNK < N_NODES ? begin + CHUNK : N_NODES;
    int s = 0;
    for (int i = begin; i < end; ++i) s += counts[i];
    sums[t] = s;
    __syncthreads();
    for (int o = 1; o < SCAN_T; o <<= 1) {
        int v = (t >= o) ? sums[t - o] : 0;
        __syncthreads();
        sums[t] += v;
        __syncthreads();
    }
    int run = sums[t] - s;  // exclusive prefix
    for (int i = begin; i < end; ++i) {
        offsets[i] = run;
        cursor[i] = run;
        run += counts[i];
    }
    if (t == SCAN_T - 1) offsets[N_NODES] = run;
}

__global__ void k_fill(const int* __restrict__ src, const int* __restrict__ dst,
                       int* cursor, int* __restrict__ csr_src) {
    int i = blockIdx.x * blockDim.x + threadIdx.x;
    if (i < N_EDGES) {
        int pos = atomicAdd(&cursor[dst[i]], 1);
        csr_src[pos] = src[i];
    } else if (i < TOT_EDGES) {
        int n = i - N_EDGES;
        int pos = atomicAdd(&cursor[n], 1);
        csr_src[pos] = n;
    }
}

// ---------------- K6: per-dst softmax + aggregation; dual-dtype store -------
__global__ __launch_bounds__(256) void k_aggregate(
        const __bf16* __restrict__ h,
        const float* __restrict__ a_src,
        const float* __restrict__ a_dst,
        const int* __restrict__ offsets,
        const int* __restrict__ csr_src,
        const float* __restrict__ bias,
        const int* __restrict__ flags,
        void* __restrict__ out) {
    int wave = threadIdx.x >> 6, lane = threadIdx.x & 63;
    int node = blockIdx.x * 4 + wave;
    if (node >= N_NODES) return;
    int base = offsets[node];
    int deg = offsets[node + 1] - base;

    float adn[HEADS];
#pragma unroll
    for (int hh = 0; hh < HEADS; ++hh) adn[hh] = a_dst[node * 4 + hh];

    // pass 1: per-head max over incoming edges
    float mx[HEADS] = {-1e30f, -1e30f, -1e30f, -1e30f};
    for (int e = lane; e < deg; e += 64) {
        int s = csr_src[base + e];
#pragma unroll
        for (int hh = 0; hh < HEADS; ++hh) {
            float l = a_src[s * 4 + hh] + adn[hh];
            l = l > 0.f ? l : NEG_SLOPE * l;
            mx[hh] = fmaxf(mx[hh], l);
        }
    }
#pragma unroll
    for (int hh = 0; hh < HEADS; ++hh)
#pragma unroll
        for (int o = 32; o >= 1; o >>= 1)
            mx[hh] = fmaxf(mx[hh], __shfl_xor(mx[hh], o, 64));

    // pass 2: per-head sum of exp
    float sm[HEADS] = {0.f, 0.f, 0.f, 0.f};
    for (int e = lane; e < deg; e += 64) {
        int s = csr_src[base + e];
#pragma unroll
        for (int hh = 0; hh < HEADS; ++hh) {
            float l = a_src[s * 4 + hh] + adn[hh];
            l = l > 0.f ? l : NEG_SLOPE * l;
            sm[hh] += __expf(l - mx[hh]);
        }
    }
#pragma unroll
    for (int hh = 0; hh < HEADS; ++hh)
#pragma unroll
        for (int o = 32; o >= 1; o >>= 1)
            sm[hh] += __shfl_xor(sm[hh], o, 64);

    // pass 3: serial over edges, 64 lanes gather+FMA 4 features each
    int head = lane >> 4;
    float m_h = mx[head];
    float inv_d = 1.f / sm[head];
    float acc0 = 0.f, acc1 = 0.f, acc2 = 0.f, acc3 = 0.f;
    const unsigned short* hs = reinterpret_cast<const unsigned short*>(h);
    for (int e = 0; e < deg; ++e) {
        int s = csr_src[base + e];
        float l = a_src[s * 4 + head] + adn[head];
        l = l > 0.f ? l : NEG_SLOPE * l;
        float alpha = __expf(l - m_h);
        ushort4 hv = *reinterpret_cast<const ushort4*>(hs + (size_t)s * OUT_DIM + lane * 4);
        acc0 += alpha * b2f(hv.x);
        acc1 += alpha * b2f(hv.y);
        acc2 += alpha * b2f(hv.z);
        acc3 += alpha * b2f(hv.w);
    }
    float v0 = acc0 * inv_d + bias[lane * 4 + 0];
    float v1 = acc1 * inv_d + bias[lane * 4 + 1];
    float v2 = acc2 * inv_d + bias[lane * 4 + 2];
    float v3 = acc3 * inv_d + bias[lane * 4 + 3];
    v0 = v0 > 0.f ? v0 : 0.f;
    v1 = v1 > 0.f ? v1 : 0.f;
    v2 = v2 > 0.f ? v2 : 0.f;
    v3 = v3 > 0.f ? v3 : 0.f;
    size_t idx = (size_t)node * OUT_DIM + lane * 4;
    if (flags[1]) {
        float4 o4 = {v0, v1, v2, v3};
        *reinterpret_cast<float4*>((float*)out + idx) = o4;
    } else {
        ushort4 o4;
        o4.x = f2b(v0); o4.y = f2b(v1); o4.z = f2b(v2); o4.w = f2b(v3);
        *reinterpret_cast<ushort4*>((unsigned short*)out + idx) = o4;
    }
}

// ---------------------------------------------------------------------------
extern "C" void kernel_launch(void* const* d_in, const int* in_sizes, int n_in,
                              void* d_out, int out_size, void* d_ws, size_t ws_size,
                              hipStream_t stream) {
    (void)out_size; (void)ws_size;
    // resolve inputs by element count, fall back to dict order
    const void* p_x = nullptr; const void* p_ei = nullptr; const void* p_W = nullptr;
    const void* p_small[3] = {nullptr, nullptr, nullptr}; int nsmall = 0;
    for (int i = 0; i < n_in; ++i) {
        switch (in_sizes[i]) {
            case N_NODES * IN_DIM:      p_x = d_in[i]; break;
            case 2 * N_EDGES:           p_ei = d_in[i]; break;
            case IN_DIM * OUT_DIM:      p_W = d_in[i]; break;
            case OUT_DIM:               if (nsmall < 3) p_small[nsmall++] = d_in[i]; break;
            default: break;
        }
    }
    if (!p_x)  p_x  = d_in[0];
    if (!p_ei) p_ei = d_in[1];
    if (!p_W)  p_W  = d_in[2];
    if (nsmall < 3) { p_small[0] = d_in[3]; p_small[1] = d_in[4]; p_small[2] = d_in[5]; }

    char* ws = (char*)d_ws;
    size_t off = 0;
    auto alloc = [&](size_t bytes) -> void* {
        void* p = ws + off;
        off = (off + bytes + 255) & ~(size_t)255;
        return p;
    };
    __bf16* x_bf  = (__bf16*)alloc((size_t)N_NODES * IN_DIM * 2);
    __bf16* W_bf  = (__bf16*)alloc((size_t)IN_DIM * OUT_DIM * 2);
    __bf16* h     = (__bf16*)alloc((size_t)N_NODES * OUT_DIM * 2);
    float* a_src  = (float*)alloc((size_t)N_NODES * HEADS * 4);
    float* a_dst  = (float*)alloc((size_t)N_NODES * HEADS * 4);
    float* att_sf = (float*)alloc(OUT_DIM * 4);
    float* att_df = (float*)alloc(OUT_DIM * 4);
    float* bias_f = (float*)alloc(OUT_DIM * 4);
    int* counts   = (int*)alloc((size_t)N_NODES * 4);
    int* offsets  = (int*)alloc((size_t)(N_NODES + 1) * 4);
    int* cursor   = (int*)alloc((size_t)N_NODES * 4);
    int* csr_src  = (int*)alloc((size_t)TOT_EDGES * 4);
    int* src32    = (int*)alloc((size_t)N_EDGES * 4);
    int* dst32    = (int*)alloc((size_t)N_EDGES * 4);
    int* flags    = (int*)alloc(8);

    k_detect<<<dim3(1), dim3(256), 0, stream>>>((const unsigned int*)p_x, (const int*)p_ei, flags);
    k_extract<<<dim3((2 * N_EDGES + 255) / 256), dim3(256), 0, stream>>>(p_ei, flags, src32, dst32);
    k_cvt_mat<<<dim3((N_NODES * IN_DIM / 4 + 255) / 256), dim3(256), 0, stream>>>(p_x, flags, x_bf, N_NODES * IN_DIM);
    k_cvt_mat<<<dim3((IN_DIM * OUT_DIM / 4 + 255) / 256), dim3(256), 0, stream>>>(p_W, flags, W_bf, IN_DIM * OUT_DIM);
    k_cvt_small<<<dim3(1), dim3(256), 0, stream>>>(p_small[0], p_small[1], p_small[2], flags, att_sf, att_df, bias_f);
    k_init<<<dim3((N_NODES + 255) / 256), dim3(256), 0, stream>>>(counts);
    k_gemm<<<dim3(N_NODES / 16), dim3(256), 0, stream>>>(x_bf, W_bf, h);
    k_att<<<dim3((N_NODES + 3) / 4), dim3(256), 0, stream>>>(h, att_sf, att_df, a_src, a_dst);
    k_hist<<<dim3((N_EDGES + 255) / 256), dim3(256), 0, stream>>>(dst32, counts);
    k_scan<<<dim3(1), dim3(SCAN_T), 0, stream>>>(counts, offsets, cursor);
    k_fill<<<dim3((TOT_EDGES + 255) / 256), dim3(256), 0, stream>>>(src32, dst32, cursor, csr_src);
    k_aggregate<<<dim3((N_NODES + 3) / 4), dim3(256), 0, stream>>>(h, a_src, a_dst, offsets, csr_src, bias_f, flags, d_out);
}

// Round 4
// 336.447 us; speedup vs baseline: 1.5125x; 1.5125x over previous
//
#include <hip/hip_runtime.h>
#include <hip/hip_bf16.h>

#define N_NODES 50000
#define N_EDGES 800000
#define TOT_EDGES (N_EDGES + N_NODES)
#define IN_DIM 256
#define OUT_DIM 256   // HEADS * HID
#define HEADS 4
#define HID 64
#define NEG_SLOPE 0.2f
#define MAXD 128      // LDS alpha-cache capacity per node (deg > MAXD -> recompute tail)

typedef __bf16 bf16x8 __attribute__((ext_vector_type(8)));
typedef float f32x4 __attribute__((ext_vector_type(4)));

__device__ __forceinline__ float b2f(unsigned short u) {
    union { float f; unsigned int i; } v; v.i = ((unsigned int)u) << 16; return v.f;
}

// ---------------- K_detect: edge_index int64 (1) vs int32 (0) ---------------
__global__ void k_detect(const int* __restrict__ ei, int* __restrict__ flags) {
    __shared__ int nz;
    if (threadIdx.x == 0) nz = 0;
    __syncthreads();
    int l = 0;
    for (int i = threadIdx.x; i < 4096; i += blockDim.x)
        if (ei[2 * i + 1] != 0) l++;
    atomicAdd(&nz, l);
    __syncthreads();
    if (threadIdx.x == 0) flags[0] = (nz == 0) ? 1 : 0;
}

// ---------------- K_wt: W fp32 [k][n] -> W_t bf16 [n][k] --------------------
__global__ void k_wt(const float* __restrict__ W, __bf16* __restrict__ Wt) {
    int k = blockIdx.x;    // 256
    int n = threadIdx.x;   // 256
    Wt[(size_t)n * IN_DIM + k] = (__bf16)W[(size_t)k * OUT_DIM + n];
}

// ---------------- K_extract_hist: split edges + dst histogram ---------------
__global__ void k_extract_hist(const void* __restrict__ ei, const int* __restrict__ flags,
                               int* __restrict__ src, int* __restrict__ dst,
                               int* __restrict__ counts) {
    int i = blockIdx.x * blockDim.x + threadIdx.x;
    if (i >= 2 * N_EDGES) return;
    int v;
    if (flags[0]) v = (int)((const long long*)ei)[i];
    else          v = ((const int*)ei)[i];
    if (i < N_EDGES) src[i] = v;
    else { dst[i - N_EDGES] = v; atomicAdd(&counts[v], 1); }
}

// ---------------- K_gemm: h = x@W (fp32 in, bf16 MFMA) + fused att logits ---
// 625 blocks x 256 thr; block = 80 rows (5 m-tiles), wave w = cols [w*64,w*64+64)
__global__ __launch_bounds__(256) void k_gemm(const float* __restrict__ x,
                                              const __bf16* __restrict__ Wt,
                                              const float* __restrict__ att_s,
                                              const float* __restrict__ att_d,
                                              __bf16* __restrict__ h,
                                              float* __restrict__ a_src,
                                              float* __restrict__ a_dst) {
    const int wave = threadIdx.x >> 6;
    const int lane = threadIdx.x & 63;
    const int c    = lane & 15;
    const int quad = lane >> 4;
    const int mbase = blockIdx.x * 80;
    const int n0    = wave * 64;

    f32x4 acc[5][4];
#pragma unroll
    for (int mt = 0; mt < 5; ++mt)
#pragma unroll
        for (int j = 0; j < 4; ++j) acc[mt][j] = (f32x4){0.f, 0.f, 0.f, 0.f};

    const float4* x4 = (const float4*)x;

    for (int k0 = 0; k0 < IN_DIM; k0 += 32) {
        bf16x8 b0 = *(const bf16x8*)(Wt + (size_t)(n0 + c)      * IN_DIM + k0 + quad * 8);
        bf16x8 b1 = *(const bf16x8*)(Wt + (size_t)(n0 + 16 + c) * IN_DIM + k0 + quad * 8);
        bf16x8 b2 = *(const bf16x8*)(Wt + (size_t)(n0 + 32 + c) * IN_DIM + k0 + quad * 8);
        bf16x8 b3 = *(const bf16x8*)(Wt + (size_t)(n0 + 48 + c) * IN_DIM + k0 + quad * 8);
        bf16x8 af[5];
#pragma unroll
        for (int mt = 0; mt < 5; ++mt) {
            int row = mbase + mt * 16 + c;
            float4 lo = x4[(size_t)row * 64 + (k0 >> 2) + quad * 2];
            float4 hi = x4[(size_t)row * 64 + (k0 >> 2) + quad * 2 + 1];
            af[mt][0] = (__bf16)lo.x; af[mt][1] = (__bf16)lo.y;
            af[mt][2] = (__bf16)lo.z; af[mt][3] = (__bf16)lo.w;
            af[mt][4] = (__bf16)hi.x; af[mt][5] = (__bf16)hi.y;
            af[mt][6] = (__bf16)hi.z; af[mt][7] = (__bf16)hi.w;
        }
#pragma unroll
        for (int mt = 0; mt < 5; ++mt) {
            acc[mt][0] = __builtin_amdgcn_mfma_f32_16x16x32_bf16(af[mt], b0, acc[mt][0], 0, 0, 0);
            acc[mt][1] = __builtin_amdgcn_mfma_f32_16x16x32_bf16(af[mt], b1, acc[mt][1], 0, 0, 0);
            acc[mt][2] = __builtin_amdgcn_mfma_f32_16x16x32_bf16(af[mt], b2, acc[mt][2], 0, 0, 0);
            acc[mt][3] = __builtin_amdgcn_mfma_f32_16x16x32_bf16(af[mt], b3, acc[mt][3], 0, 0, 0);
        }
    }

    // epilogue: store h (bf16) + fused per-node attention logits
    // col of acc[mt][j] lane slot = n0 + j*16 + c; head = wave; f = col - n0
    float as0 = att_s[n0 + c],      as1 = att_s[n0 + 16 + c];
    float as2 = att_s[n0 + 32 + c], as3 = att_s[n0 + 48 + c];
    float ad0 = att_d[n0 + c],      ad1 = att_d[n0 + 16 + c];
    float ad2 = att_d[n0 + 32 + c], ad3 = att_d[n0 + 48 + c];
#pragma unroll
    for (int mt = 0; mt < 5; ++mt) {
#pragma unroll
        for (int r = 0; r < 4; ++r) {
            int row = mbase + mt * 16 + quad * 4 + r;
            __bf16* orow = h + (size_t)row * OUT_DIM + n0 + c;
            orow[0]  = (__bf16)acc[mt][0][r];
            orow[16] = (__bf16)acc[mt][1][r];
            orow[32] = (__bf16)acc[mt][2][r];
            orow[48] = (__bf16)acc[mt][3][r];
            float pS = acc[mt][0][r] * as0 + acc[mt][1][r] * as1
                     + acc[mt][2][r] * as2 + acc[mt][3][r] * as3;
            float pD = acc[mt][0][r] * ad0 + acc[mt][1][r] * ad1
                     + acc[mt][2][r] * ad2 + acc[mt][3][r] * ad3;
#pragma unroll
            for (int o = 8; o >= 1; o >>= 1) {
                pS += __shfl_xor(pS, o, 64);
                pD += __shfl_xor(pD, o, 64);
            }
            if (c == 0) {
                a_src[row * 4 + wave] = pS;
                a_dst[row * 4 + wave] = pD;
            }
        }
    }
}

// ---------------- scan (3 kernels, coalesced) -------------------------------
#define SBLK 1024
#define NBLK ((N_NODES + SBLK - 1) / SBLK)   // 49
__global__ __launch_bounds__(1024) void k_scanA(const int* __restrict__ counts,
                                                int* __restrict__ loc,
                                                int* __restrict__ bsum) {
    __shared__ int s[SBLK];
    int t = threadIdx.x, idx = blockIdx.x * SBLK + t;
    int cval = (idx < N_NODES) ? counts[idx] + 1 : 0;  // +1 = self loop
    s[t] = cval;
    __syncthreads();
    for (int off = 1; off < SBLK; off <<= 1) {
        int v = (t >= off) ? s[t - off] : 0;
        __syncthreads();
        s[t] += v;
        __syncthreads();
    }
    if (idx < N_NODES) loc[idx] = s[t] - cval;   // block-local exclusive
    if (t == SBLK - 1) bsum[blockIdx.x] = s[t];
}

__global__ void k_scanB(const int* __restrict__ bsum, int* __restrict__ bpref,
                        int* __restrict__ offsets) {
    int lane = threadIdx.x;  // 64
    int v = (lane < NBLK) ? bsum[lane] : 0;
    int orig = v;
#pragma unroll
    for (int off = 1; off < 64; off <<= 1) {
        int u = __shfl_up(v, off, 64);
        if (lane >= off) v += u;
    }
    if (lane < NBLK) bpref[lane] = v - orig;
    if (lane == 0) offsets[N_NODES] = TOT_EDGES;
}

__global__ void k_scanC(const int* __restrict__ loc, const int* __restrict__ bpref,
                        int* __restrict__ offsets, int* __restrict__ cursor) {
    int idx = blockIdx.x * blockDim.x + threadIdx.x;
    if (idx < N_NODES) {
        int o = loc[idx] + bpref[idx >> 10];
        offsets[idx] = o;
        cursor[idx] = o;
    }
}

__global__ void k_fill(const int* __restrict__ src, const int* __restrict__ dst,
                       int* cursor, int* __restrict__ csr_src) {
    int i = blockIdx.x * blockDim.x + threadIdx.x;
    if (i < N_EDGES) {
        int pos = atomicAdd(&cursor[dst[i]], 1);
        csr_src[pos] = src[i];
    } else if (i < TOT_EDGES) {
        int n = i - N_EDGES;
        int pos = atomicAdd(&cursor[n], 1);
        csr_src[pos] = n;
    }
}

// ---------------- K_aggregate v2: LDS alpha cache + unrolled gather ---------
__global__ __launch_bounds__(256) void k_aggregate(
        const __bf16* __restrict__ h,
        const float* __restrict__ a_src,
        const float* __restrict__ a_dst,
        const int* __restrict__ offsets,
        const int* __restrict__ csr_src,
        const float* __restrict__ bias,
        float* __restrict__ out) {
    __shared__ float lds[4][MAXD][4];
    int wave = threadIdx.x >> 6, lane = threadIdx.x & 63;
    int node = blockIdx.x * 4 + wave;
    if (node >= N_NODES) return;
    int base = offsets[node];
    int deg  = offsets[node + 1] - base;

    const float4* as4 = (const float4*)a_src;
    float4 ad = ((const float4*)a_dst)[node];

    // pass 1: leaky logits -> LDS, running max
    float4 mx = {-1e30f, -1e30f, -1e30f, -1e30f};
    for (int e = lane; e < deg; e += 64) {
        int s = csr_src[base + e];
        float4 av = as4[s];
        float4 l;
        l.x = av.x + ad.x; l.x = l.x > 0.f ? l.x : NEG_SLOPE * l.x;
        l.y = av.y + ad.y; l.y = l.y > 0.f ? l.y : NEG_SLOPE * l.y;
        l.z = av.z + ad.z; l.z = l.z > 0.f ? l.z : NEG_SLOPE * l.z;
        l.w = av.w + ad.w; l.w = l.w > 0.f ? l.w : NEG_SLOPE * l.w;
        if (e < MAXD) {
            lds[wave][e][0] = l.x; lds[wave][e][1] = l.y;
            lds[wave][e][2] = l.z; lds[wave][e][3] = l.w;
        }
        mx.x = fmaxf(mx.x, l.x); mx.y = fmaxf(mx.y, l.y);
        mx.z = fmaxf(mx.z, l.z); mx.w = fmaxf(mx.w, l.w);
    }
#pragma unroll
    for (int o = 32; o >= 1; o >>= 1) {
        mx.x = fmaxf(mx.x, __shfl_xor(mx.x, o, 64));
        mx.y = fmaxf(mx.y, __shfl_xor(mx.y, o, 64));
        mx.z = fmaxf(mx.z, __shfl_xor(mx.z, o, 64));
        mx.w = fmaxf(mx.w, __shfl_xor(mx.w, o, 64));
    }

    // pass 2: alpha = exp(l - mx) -> LDS (overwrite), running sum
    float4 sm = {0.f, 0.f, 0.f, 0.f};
    for (int e = lane; e < deg; e += 64) {
        float4 l;
        if (e < MAXD) {
            l.x = lds[wave][e][0]; l.y = lds[wave][e][1];
            l.z = lds[wave][e][2]; l.w = lds[wave][e][3];
        } else {
            int s = csr_src[base + e];
            float4 av = as4[s];
            l.x = av.x + ad.x; l.x = l.x > 0.f ? l.x : NEG_SLOPE * l.x;
            l.y = av.y + ad.y; l.y = l.y > 0.f ? l.y : NEG_SLOPE * l.y;
            l.z = av.z + ad.z; l.z = l.z > 0.f ? l.z : NEG_SLOPE * l.z;
            l.w = av.w + ad.w; l.w = l.w > 0.f ? l.w : NEG_SLOPE * l.w;
        }
        float4 e4;
        e4.x = __expf(l.x - mx.x); e4.y = __expf(l.y - mx.y);
        e4.z = __expf(l.z - mx.z); e4.w = __expf(l.w - mx.w);
        sm.x += e4.x; sm.y += e4.y; sm.z += e4.z; sm.w += e4.w;
        if (e < MAXD) {
            lds[wave][e][0] = e4.x; lds[wave][e][1] = e4.y;
            lds[wave][e][2] = e4.z; lds[wave][e][3] = e4.w;
        }
    }
    // zero-pad LDS up to multiple of 4
    int padEnd = (deg + 3) & ~3;
    if (padEnd > MAXD) padEnd = MAXD;
    for (int e = deg + lane; e < padEnd; e += 64) {
        lds[wave][e][0] = 0.f; lds[wave][e][1] = 0.f;
        lds[wave][e][2] = 0.f; lds[wave][e][3] = 0.f;
    }
#pragma unroll
    for (int o = 32; o >= 1; o >>= 1) {
        sm.x += __shfl_xor(sm.x, o, 64);
        sm.y += __shfl_xor(sm.y, o, 64);
        sm.z += __shfl_xor(sm.z, o, 64);
        sm.w += __shfl_xor(sm.w, o, 64);
    }

    int head = lane >> 4;
    float mh  = head == 0 ? mx.x : head == 1 ? mx.y : head == 2 ? mx.z : mx.w;
    float smh = head == 0 ? sm.x : head == 1 ? sm.y : head == 2 ? sm.z : sm.w;
    float adh = head == 0 ? ad.x : head == 1 ? ad.y : head == 2 ? ad.z : ad.w;
    float inv_d = 1.f / smh;

    // pass 3: unroll-by-4 gather + FMA (alpha from LDS)
    float acc0 = 0.f, acc1 = 0.f, acc2 = 0.f, acc3 = 0.f;
    const unsigned short* hs = reinterpret_cast<const unsigned short*>(h);
    int degc = deg < MAXD ? deg : MAXD;
    int rEnd = (degc + 3) & ~3;
    for (int e = 0; e < rEnd; e += 4) {
        int s0 = csr_src[base + e];
        int s1 = csr_src[base + ((e + 1 < deg) ? e + 1 : 0)];
        int s2 = csr_src[base + ((e + 2 < deg) ? e + 2 : 0)];
        int s3 = csr_src[base + ((e + 3 < deg) ? e + 3 : 0)];
        float al0 = lds[wave][e][head];
        float al1 = lds[wave][e + 1][head];
        float al2 = lds[wave][e + 2][head];
        float al3 = lds[wave][e + 3][head];
        ushort4 h0 = *(const ushort4*)(hs + (size_t)s0 * OUT_DIM + lane * 4);
        ushort4 h1 = *(const ushort4*)(hs + (size_t)s1 * OUT_DIM + lane * 4);
        ushort4 h2 = *(const ushort4*)(hs + (size_t)s2 * OUT_DIM + lane * 4);
        ushort4 h3 = *(const ushort4*)(hs + (size_t)s3 * OUT_DIM + lane * 4);
        acc0 += al0 * b2f(h0.x) + al1 * b2f(h1.x) + al2 * b2f(h2.x) + al3 * b2f(h3.x);
        acc1 += al0 * b2f(h0.y) + al1 * b2f(h1.y) + al2 * b2f(h2.y) + al3 * b2f(h3.y);
        acc2 += al0 * b2f(h0.z) + al1 * b2f(h1.z) + al2 * b2f(h2.z) + al3 * b2f(h3.z);
        acc3 += al0 * b2f(h0.w) + al1 * b2f(h1.w) + al2 * b2f(h2.w) + al3 * b2f(h3.w);
    }
    // rare tail: deg > MAXD -> recompute alpha
    for (int e = MAXD; e < deg; ++e) {
        int s = csr_src[base + e];
        float a = a_src[s * 4 + head] + adh;
        a = a > 0.f ? a : NEG_SLOPE * a;
        float al = __expf(a - mh);
        ushort4 hv = *(const ushort4*)(hs + (size_t)s * OUT_DIM + lane * 4);
        acc0 += al * b2f(hv.x); acc1 += al * b2f(hv.y);
        acc2 += al * b2f(hv.z); acc3 += al * b2f(hv.w);
    }

    float4 bv = ((const float4*)bias)[lane];
    float v0 = acc0 * inv_d + bv.x;
    float v1 = acc1 * inv_d + bv.y;
    float v2 = acc2 * inv_d + bv.z;
    float v3 = acc3 * inv_d + bv.w;
    float4 o4;
    o4.x = v0 > 0.f ? v0 : 0.f;
    o4.y = v1 > 0.f ? v1 : 0.f;
    o4.z = v2 > 0.f ? v2 : 0.f;
    o4.w = v3 > 0.f ? v3 : 0.f;
    ((float4*)out)[(size_t)node * 64 + lane] = o4;
}

// ---------------------------------------------------------------------------
extern "C" void kernel_launch(void* const* d_in, const int* in_sizes, int n_in,
                              void* d_out, int out_size, void* d_ws, size_t ws_size,
                              hipStream_t stream) {
    (void)out_size; (void)ws_size;
    const void* p_x = nullptr; const void* p_ei = nullptr; const void* p_W = nullptr;
    const void* p_small[3] = {nullptr, nullptr, nullptr}; int nsmall = 0;
    for (int i = 0; i < n_in; ++i) {
        switch (in_sizes[i]) {
            case N_NODES * IN_DIM:      p_x = d_in[i]; break;
            case 2 * N_EDGES:           p_ei = d_in[i]; break;
            case IN_DIM * OUT_DIM:      p_W = d_in[i]; break;
            case OUT_DIM:               if (nsmall < 3) p_small[nsmall++] = d_in[i]; break;
            default: break;
        }
    }
    if (!p_x)  p_x  = d_in[0];
    if (!p_ei) p_ei = d_in[1];
    if (!p_W)  p_W  = d_in[2];
    if (nsmall < 3) { p_small[0] = d_in[3]; p_small[1] = d_in[4]; p_small[2] = d_in[5]; }

    char* ws = (char*)d_ws;
    size_t off = 0;
    auto alloc = [&](size_t bytes) -> void* {
        void* p = ws + off;
        off = (off + bytes + 255) & ~(size_t)255;
        return p;
    };
    __bf16* Wt    = (__bf16*)alloc((size_t)IN_DIM * OUT_DIM * 2);
    __bf16* h     = (__bf16*)alloc((size_t)N_NODES * OUT_DIM * 2);
    float* a_src  = (float*)alloc((size_t)N_NODES * HEADS * 4);
    float* a_dst  = (float*)alloc((size_t)N_NODES * HEADS * 4);
    int* counts   = (int*)alloc((size_t)N_NODES * 4);
    int* loc      = (int*)alloc((size_t)N_NODES * 4);
    int* bsum     = (int*)alloc(NBLK * 4);
    int* bpref    = (int*)alloc(NBLK * 4);
    int* offsets  = (int*)alloc((size_t)(N_NODES + 1) * 4);
    int* cursor   = (int*)alloc((size_t)N_NODES * 4);
    int* csr_src  = (int*)alloc((size_t)TOT_EDGES * 4);
    int* src32    = (int*)alloc((size_t)N_EDGES * 4);
    int* dst32    = (int*)alloc((size_t)N_EDGES * 4);
    int* flags    = (int*)alloc(8);

    const float* x_f    = (const float*)p_x;
    const float* W_f    = (const float*)p_W;
    const float* att_sf = (const float*)p_small[0];
    const float* att_df = (const float*)p_small[1];
    const float* bias_f = (const float*)p_small[2];
    float* out_f        = (float*)d_out;

    hipMemsetAsync(counts, 0, (size_t)N_NODES * 4, stream);
    k_detect<<<dim3(1), dim3(256), 0, stream>>>((const int*)p_ei, flags);
    k_wt<<<dim3(IN_DIM), dim3(OUT_DIM), 0, stream>>>(W_f, Wt);
    k_extract_hist<<<dim3((2 * N_EDGES + 255) / 256), dim3(256), 0, stream>>>(p_ei, flags, src32, dst32, counts);
    k_gemm<<<dim3(N_NODES / 80), dim3(256), 0, stream>>>(x_f, Wt, att_sf, att_df, h, a_src, a_dst);
    k_scanA<<<dim3(NBLK), dim3(SBLK), 0, stream>>>(counts, loc, bsum);
    k_scanB<<<dim3(1), dim3(64), 0, stream>>>(bsum, bpref, offsets);
    k_scanC<<<dim3((N_NODES + 255) / 256), dim3(256), 0, stream>>>(loc, bpref, offsets, cursor);
    k_fill<<<dim3((TOT_EDGES + 255) / 256), dim3(256), 0, stream>>>(src32, dst32, cursor, csr_src);
    k_aggregate<<<dim3((N_NODES + 3) / 4), dim3(256), 0, stream>>>(h, a_src, a_dst, offsets, csr_src, bias_f, out_f);
}